// Round 1
// baseline (7172.031 us; speedup 1.0000x reference)
//
#include <hip/hip_runtime.h>
#include <math.h>

// ---------------- problem constants ----------------
constexpr int CB=2048, CMA=6, CS=11, CSP=10, CD=256, CH=4, CDH=64, CL=12;
constexpr int CNREL=500, CNTYPE=1000, CNODE=100000, CVOC=99000, CNCLS=1500;
constexpr int NN  = CB*CMA;     // 12288 GAT nodes
constexpr int NSR = CB*CS;      // 22528 sequence rows
constexpr int NTAB= 3+CNTYPE;   // 1003 distinct type-embedding rows
constexpr float BIGF = 1000000.0f;

__device__ __forceinline__ float lreluf(float x){ return x>=0.f ? x : 0.2f*x; }
__device__ __forceinline__ float eluf1(float x){ return x>0.f ? x : expm1f(x); }
__device__ __forceinline__ float geluf(float x){ return 0.5f*x*(1.f+erff(x*0.70710678118654752f)); }

// block=256 reductions (4 waves)
__device__ __forceinline__ float blk_sum(float v, float* red){
#pragma unroll
  for (int o=32;o;o>>=1) v += __shfl_down(v,o,64);
  __syncthreads();
  if ((threadIdx.x&63)==0) red[threadIdx.x>>6]=v;
  __syncthreads();
  return red[0]+red[1]+red[2]+red[3];
}
__device__ __forceinline__ float blk_max(float v, float* red){
#pragma unroll
  for (int o=32;o;o>>=1) v = fmaxf(v,__shfl_down(v,o,64));
  __syncthreads();
  if ((threadIdx.x&63)==0) red[threadIdx.x>>6]=v;
  __syncthreads();
  return fmaxf(fmaxf(red[0],red[1]),fmaxf(red[2],red[3]));
}

// ---------------- type prep: itt[n][sp] ----------------
__global__ __launch_bounds__(256)
void k_typeprep(const int* __restrict__ input_ids, const int* __restrict__ ent_types,
                int* __restrict__ itt)
{
  int idx = blockIdx.x*256 + threadIdx.x;
  if (idx >= NN*CSP) return;
  int n = idx / CSP, sp = idx % CSP;
  int b = n / CMA, ma = n % CMA;
  int id = input_ids[b*CS + 2*ma] - CNREL;            // in [0, 3+E)
  itt[idx] = (id < 3) ? id : ent_types[(size_t)(id-3)*(CSP+1) + sp + 1];
}

// ---------------- distinct-row table: TW = T@W, Ts=TW@a_src, Tt=TW@a_dst ----------------
__global__ __launch_bounds__(256)
void k_tables(const float* __restrict__ emb, const float* __restrict__ W,
              const float* __restrict__ asrc, const float* __restrict__ adst,
              float* __restrict__ TW, float* __restrict__ Ts, float* __restrict__ Tt)
{
  __shared__ float row[CD];
  __shared__ float red[8];
  const int r = blockIdx.x, d = threadIdx.x;
  const int nrow = (r<3) ? r : (CVOC + (r-3));
  row[d] = emb[(size_t)nrow*CD + d];
  __syncthreads();
  float acc = 0.f;
  for (int k=0;k<CD;k+=4){
    const float4 hv = *reinterpret_cast<const float4*>(&row[k]);
    acc = fmaf(hv.x, W[(size_t)(k+0)*CD+d],
          fmaf(hv.y, W[(size_t)(k+1)*CD+d],
          fmaf(hv.z, W[(size_t)(k+2)*CD+d],
          fmaf(hv.w, W[(size_t)(k+3)*CD+d], acc))));
  }
  TW[(size_t)r*CD+d] = acc;
  float s = blk_sum(acc*asrc[d], red);
  float t = blk_sum(acc*adst[d], red);
  if (d==0){ Ts[r]=s; Tt[r]=t; }
}

// ---------------- g1 -> g1@W2a (+s,t,rowsum) for GAT2 layer-1 gather ----------------
__global__ __launch_bounds__(256)
void k_g1post(const float* __restrict__ g1, const float* __restrict__ W,
              const float* __restrict__ asrc, const float* __restrict__ adst,
              float* __restrict__ GW, float* __restrict__ Gs, float* __restrict__ Gt,
              float* __restrict__ Grs)
{
  __shared__ float row[CD];
  __shared__ float red[8];
  const int n = blockIdx.x, d = threadIdx.x;
  float v = g1[(size_t)n*CD + d];
  row[d] = v;
  __syncthreads();
  float acc = 0.f;
  for (int k=0;k<CD;k+=4){
    const float4 hv = *reinterpret_cast<const float4*>(&row[k]);
    acc = fmaf(hv.x, W[(size_t)(k+0)*CD+d],
          fmaf(hv.y, W[(size_t)(k+1)*CD+d],
          fmaf(hv.z, W[(size_t)(k+2)*CD+d],
          fmaf(hv.w, W[(size_t)(k+3)*CD+d], acc))));
  }
  GW[(size_t)n*CD+d] = acc;
  float s  = blk_sum(acc*asrc[d], red);
  float t  = blk_sum(acc*adst[d], red);
  float rs = blk_sum(v, red);
  if (d==0){ Gs[n]=s; Gt[n]=t; Grs[n]=rs; }
}

// ---------------- GAT masked softmax (thread i owns row i) ----------------
template<int P>
__device__ __forceinline__ void gat_softmax(float (*att)[P+1], const float* sA,
                                            const float* tA, const int* sg)
{
  const int i = threadIdx.x;
  if (i < P){
    if (sg[i]){
      float si = sA[i];
      float e[P];
      float m = -3.0e38f;
#pragma unroll
      for (int j=0;j<P;j++){
        e[j] = 0.f;
        if (sg[j]){ e[j] = lreluf(si + tA[j]); m = fmaxf(m, e[j]); }
      }
      float s = 0.f;
#pragma unroll
      for (int j=0;j<P;j++){
        float w = sg[j] ? expf(e[j]-m) : 0.f;   // masked j: exactly 0 (matches exp(-1e6) underflow)
        att[i][j] = w; s += w;
      }
      float inv = 1.f/s;
#pragma unroll
      for (int j=0;j<P;j++) att[i][j] *= inv;
    } else {
      // masked rows: output dropped by pos-mask; 0 keeps layer-2 s/t finite & harmless
#pragma unroll
      for (int j=0;j<P;j++) att[i][j] = 0.f;
    }
  }
}

// ---------------- fused per-node 2-layer GAT ----------------
// Layer-1 hW/s/t come pre-gathered (TW tables; for P=15 also GW from g1).
template<int P>
__global__ __launch_bounds__(256)
void k_gat(const int* __restrict__ itt,
           const float* __restrict__ TW, const float* __restrict__ Ts, const float* __restrict__ Tt,
           const float* __restrict__ GW, const float* __restrict__ Gs, const float* __restrict__ Gt,
           const float* __restrict__ Grs, const int* __restrict__ l2m,
           const float* __restrict__ W2, const float* __restrict__ as2, const float* __restrict__ ad2,
           float* __restrict__ gout)
{
  __shared__ float hW[P][CD];
  __shared__ float hb[P][CD];
  __shared__ float att[P][P+1];
  __shared__ float sA[P], tA[P];
  __shared__ int   sg[P], ridx[P];
  __shared__ float red[8];
  const int n = blockIdx.x;
  const int d = threadIdx.x;

  if (d < P){
    if (d < CSP){
      int it = itt[n*CSP + d];
      int r = (it < 3) ? it : (it - (CVOC - 3));
      ridx[d]=r; sg[d]=(it>0); sA[d]=Ts[r]; tA[d]=Tt[r];
    } else {
      int ma = n % CMA;
      int m = l2m[ma*(CMA-1) + (d - CSP)];
      int nb = (n / CMA)*CMA + m;
      ridx[d]=nb; sg[d]=(Grs[nb]!=0.f); sA[d]=Gs[nb]; tA[d]=Gt[nb];
    }
  }
  __syncthreads();
#pragma unroll
  for (int i=0;i<P;i++){
    const float* src = (i<CSP) ? TW : GW;
    hW[i][d] = src[(size_t)ridx[i]*CD + d];
  }
  __syncthreads();
  gat_softmax<P>(att, sA, tA, sg);
  __syncthreads();
  // h = elu(att @ hW)
#pragma unroll
  for (int i=0;i<P;i++){
    float a = 0.f;
#pragma unroll
    for (int j=0;j<P;j++) a = fmaf(att[i][j], hW[j][d], a);
    hb[i][d] = eluf1(a);
  }
  __syncthreads();
  // layer-2: hW2[i][d] = sum_k h[i][k]*W2[k][d]  (W2 streamed once per block)
  float acc[P];
#pragma unroll
  for (int i=0;i<P;i++) acc[i]=0.f;
  for (int k=0;k<CD;k+=4){
    float w0=W2[(size_t)(k+0)*CD+d], w1=W2[(size_t)(k+1)*CD+d];
    float w2v=W2[(size_t)(k+2)*CD+d], w3=W2[(size_t)(k+3)*CD+d];
#pragma unroll
    for (int i=0;i<P;i++){
      const float4 hv = *reinterpret_cast<const float4*>(&hb[i][k]);
      acc[i] = fmaf(hv.x,w0,fmaf(hv.y,w1,fmaf(hv.z,w2v,fmaf(hv.w,w3,acc[i]))));
    }
  }
  // s2,t2 block reductions
  const float asv = as2[d], adv = ad2[d];
#pragma unroll
  for (int i=0;i<P;i++){
    float ps = acc[i]*asv, pt = acc[i]*adv;
#pragma unroll
    for (int o=32;o;o>>=1){ ps += __shfl_down(ps,o,64); pt += __shfl_down(pt,o,64); }
    __syncthreads();
    if ((d&63)==0){ red[d>>6]=ps; red[4+(d>>6)]=pt; }
    __syncthreads();
    if (d==0){ sA[i]=red[0]+red[1]+red[2]+red[3]; tA[i]=red[4]+red[5]+red[6]+red[7]; }
  }
#pragma unroll
  for (int i=0;i<P;i++) hW[i][d] = acc[i];
  __syncthreads();
  gat_softmax<P>(att, sA, tA, sg);
  __syncthreads();
  float denom = 0.f;
#pragma unroll
  for (int i=0;i<P;i++) denom += (float)sg[i];
  denom = fmaxf(denom, 1.f);
  float o = 0.f;
#pragma unroll
  for (int i=0;i<P;i++){
    if (sg[i]){
      float a = 0.f;
#pragma unroll
      for (int j=0;j<P;j++) a = fmaf(att[i][j], hW[j][d], a);
      o += eluf1(a);
    }
  }
  gout[(size_t)n*CD + d] = o/denom;
}

// ---------------- build x0 = emb_out after g2 & mask-row substitution ----------------
__global__ __launch_bounds__(256)
void k_x0(const int* __restrict__ input_ids, const int* __restrict__ mask_pos,
          const int* __restrict__ mask_type, const float* __restrict__ emb,
          const float* __restrict__ g2, const float* __restrict__ g,
          const float* __restrict__ bta, float* __restrict__ x)
{
  __shared__ float red[8];
  const int row = blockIdx.x;
  const int b = row / CS, s = row % CS;
  const int d = threadIdx.x;
  float* xrow = x + (size_t)row*CD;
  if (s == mask_pos[b]){
    int mm = (mask_type[b]==1) ? 2 : 1;
    xrow[d] = emb[(size_t)mm*CD + d];
  } else if ((s & 1) == 0){
    xrow[d] = g2[(size_t)(b*CMA + (s>>1))*CD + d];
  } else {
    float v = emb[(size_t)input_ids[row]*CD + d];
    float m = blk_sum(v, red)*(1.f/CD);
    float dv = v - m;
    float var = blk_sum(dv*dv, red)*(1.f/CD);
    xrow[d] = dv/sqrtf(var+1e-12f)*g[d] + bta[d];
  }
}

// ---------------- generic tiled f32 GEMM: C = act(A@B + bias + res) ----------------
// A: MxK row-major, B: KxN row-major. M%64==0, N%64==0, K%16==0 (guaranteed here).
template<int ACT, bool BIAS, bool RES>
__global__ __launch_bounds__(256)
void k_gemm(const float* __restrict__ A, const float* __restrict__ Bm,
            const float* __restrict__ bias, const float* __restrict__ res,
            float* __restrict__ C, int M, int N, int K)
{
  __shared__ alignas(16) float As[16][68];
  __shared__ alignas(16) float Bs[16][68];
  const int bn = blockIdx.x*64, bm = blockIdx.y*64;
  const int tid = threadIdx.x;
  const int tx = tid & 15, ty = tid >> 4;
  const int ar = tid >> 2, ak = (tid & 3)*4;   // A loader: row, k4
  const int bk = tid >> 4, bnl = (tid & 15)*4; // B loader: k, n4
  const float* Aptr = A + (size_t)(bm + ar)*K + ak;
  const float* Bptr = Bm + (size_t)bk*N + bn + bnl;
  float acc[4][4] = {};
  for (int k0=0;k0<K;k0+=16){
    float4 a4 = *reinterpret_cast<const float4*>(Aptr + k0);
    float4 b4 = *reinterpret_cast<const float4*>(Bptr + (size_t)k0*N);
    As[ak+0][ar]=a4.x; As[ak+1][ar]=a4.y; As[ak+2][ar]=a4.z; As[ak+3][ar]=a4.w;
    *reinterpret_cast<float4*>(&Bs[bk][bnl]) = b4;
    __syncthreads();
#pragma unroll
    for (int kk=0;kk<16;kk++){
      float4 av4 = *reinterpret_cast<const float4*>(&As[kk][ty*4]);
      float4 bv4 = *reinterpret_cast<const float4*>(&Bs[kk][tx*4]);
      float a_[4] = {av4.x,av4.y,av4.z,av4.w};
      float b_[4] = {bv4.x,bv4.y,bv4.z,bv4.w};
#pragma unroll
      for (int i=0;i<4;i++)
#pragma unroll
        for (int j=0;j<4;j++) acc[i][j] = fmaf(a_[i], b_[j], acc[i][j]);
    }
    __syncthreads();
  }
#pragma unroll
  for (int i=0;i<4;i++){
    const int row = bm + ty*4 + i;
    float* Crow = C + (size_t)row*N + bn + tx*4;
    const float* Rrow = RES ? (res + (size_t)row*N + bn + tx*4) : nullptr;
#pragma unroll
    for (int j=0;j<4;j++){
      float v = acc[i][j];
      if (BIAS) v += bias[bn + tx*4 + j];
      if (RES)  v += Rrow[j];
      if (ACT==1) v = geluf(v);
      Crow[j] = v;
    }
  }
}

// ---------------- fused per-(b,h) attention with edge embeddings ----------------
__global__ __launch_bounds__(128)
void k_attn(const float* __restrict__ qkv, const int* __restrict__ elab,
            const float* __restrict__ ektab, const float* __restrict__ evtab,
            const float* __restrict__ imask, float* __restrict__ ctx)
{
  __shared__ float qs[CS][CDH], ks[CS][CDH], vs[CS][CDH];
  __shared__ float at[CS][CS+1];
  __shared__ int   lab[CS*CS];
  __shared__ float im[CS];
  const int bh = blockIdx.x, b = bh >> 2, h = bh & 3;
  const int tid = threadIdx.x;
  const float* qb = qkv + (size_t)b*CS*(3*CD) + h*CDH;
  for (int idx=tid; idx<CS*CDH; idx+=128){
    int i = idx>>6, dd = idx&63;
    qs[i][dd] = qb[(size_t)i*768 + dd];
    ks[i][dd] = qb[(size_t)i*768 + CD + dd];
    vs[i][dd] = qb[(size_t)i*768 + 2*CD + dd];
  }
  for (int idx=tid; idx<CS*CS; idx+=128) lab[idx] = elab[(size_t)b*CS*CS + idx];
  if (tid < CS) im[tid] = imask[b*CS + tid];
  __syncthreads();
  if (tid < CS*CS){
    int i = tid/CS, j = tid%CS;
    int l = lab[tid];
    float accq = 0.f;
#pragma unroll
    for (int dd=0;dd<CDH;dd++) accq = fmaf(qs[i][dd], ks[j][dd], accq);
    float acce = 0.f;
    if (l > 0){
      const float* ek = ektab + (size_t)l*CDH;
#pragma unroll
      for (int dd=0;dd<CDH;dd++) acce = fmaf(qs[i][dd], ek[dd], acce);
    }
    float amv = BIGF*(im[i]*im[j]-1.f);
    at[i][j] = (accq+acce)*0.125f + amv;
  }
  __syncthreads();
  if (tid < CS){
    float m = -3.0e38f;
#pragma unroll
    for (int j=0;j<CS;j++) m = fmaxf(m, at[tid][j]);
    float e[CS]; float s = 0.f;
#pragma unroll
    for (int j=0;j<CS;j++){ e[j] = expf(at[tid][j]-m); s += e[j]; }
    float inv = 1.f/s;
#pragma unroll
    for (int j=0;j<CS;j++) at[tid][j] = e[j]*inv;
  }
  __syncthreads();
  for (int idx=tid; idx<CS*CDH; idx+=128){
    int i = idx>>6, dd = idx&63;
    float a = 0.f;
#pragma unroll
    for (int j=0;j<CS;j++){
      int l = lab[i*CS+j];
      float vv = vs[j][dd];
      if (l > 0) vv += evtab[(size_t)l*CDH + dd];
      a = fmaf(at[i][j], vv, a);
    }
    ctx[((size_t)b*CS + i)*CD + h*CDH + dd] = a;
  }
}

// ---------------- row LayerNorm (two-pass, D=256) ----------------
__global__ __launch_bounds__(256)
void k_ln(const float* __restrict__ src, float* __restrict__ dst,
          const float* __restrict__ g, const float* __restrict__ bta, float eps)
{
  __shared__ float red[8];
  const int row = blockIdx.x, d = threadIdx.x;
  float v = src[(size_t)row*CD + d];
  float m = blk_sum(v, red)*(1.f/CD);
  float dv = v - m;
  float var = blk_sum(dv*dv, red)*(1.f/CD);
  dst[(size_t)row*CD + d] = dv/sqrtf(var+eps)*g[d] + bta[d];
}

// ---------------- head: hm = LN(gelu(enc_out[b, mask_pos[b]])) ----------------
__global__ __launch_bounds__(256)
void k_head(const float* __restrict__ x, const int* __restrict__ mask_pos,
            const float* __restrict__ g, const float* __restrict__ bta,
            float* __restrict__ hm)
{
  __shared__ float red[8];
  const int b = blockIdx.x, d = threadIdx.x;
  float v = geluf(x[((size_t)b*CS + mask_pos[b])*CD + d]);
  float m = blk_sum(v, red)*(1.f/CD);
  float dv = v - m;
  float var = blk_sum(dv*dv, red)*(1.f/CD);
  hm[(size_t)b*CD + d] = dv/sqrtf(var+1e-7f)*g[d] + bta[d];
}

// ---------------- classifier: fc[b][c] = hm[b] . emb_row(c) + bias(c) ----------------
__global__ __launch_bounds__(256)
void k_fc(const float* __restrict__ hm, const float* __restrict__ emb,
          const float* __restrict__ fc2b, const float* __restrict__ fc3b,
          float* __restrict__ out)
{
  __shared__ alignas(16) float As[32][36];
  __shared__ alignas(16) float Bs[32][68];
  const int bn = blockIdx.x*64, bm = blockIdx.y*32;
  const int tid = threadIdx.x;
  const int tx = tid & 15, ty = tid >> 4;
  const int ar = tid >> 3, ak = (tid & 7)*4;   // A loader
  const int bnl = tid >> 2, bk8 = (tid & 3)*8; // B loader
  const int c = bn + bnl;
  const float* brow = nullptr;
  if (c < CNCLS){
    int rr = (c < CNREL) ? (3 + c) : (CVOC + (c - CNREL));
    brow = emb + (size_t)rr*CD;
  }
  float acc[2][4] = {};
  for (int k0=0;k0<CD;k0+=32){
    float4 a4 = *reinterpret_cast<const float4*>(hm + (size_t)(bm+ar)*CD + k0 + ak);
    As[ak+0][ar]=a4.x; As[ak+1][ar]=a4.y; As[ak+2][ar]=a4.z; As[ak+3][ar]=a4.w;
    float4 b0 = make_float4(0.f,0.f,0.f,0.f), b1 = make_float4(0.f,0.f,0.f,0.f);
    if (brow){
      b0 = *reinterpret_cast<const float4*>(brow + k0 + bk8);
      b1 = *reinterpret_cast<const float4*>(brow + k0 + bk8 + 4);
    }
    Bs[bk8+0][bnl]=b0.x; Bs[bk8+1][bnl]=b0.y; Bs[bk8+2][bnl]=b0.z; Bs[bk8+3][bnl]=b0.w;
    Bs[bk8+4][bnl]=b1.x; Bs[bk8+5][bnl]=b1.y; Bs[bk8+6][bnl]=b1.z; Bs[bk8+7][bnl]=b1.w;
    __syncthreads();
#pragma unroll
    for (int kk=0;kk<32;kk++){
      float a0 = As[kk][ty*2+0], a1 = As[kk][ty*2+1];
      float4 bv4 = *reinterpret_cast<const float4*>(&Bs[kk][tx*4]);
      float b_[4] = {bv4.x,bv4.y,bv4.z,bv4.w};
#pragma unroll
      for (int j=0;j<4;j++){
        acc[0][j] = fmaf(a0, b_[j], acc[0][j]);
        acc[1][j] = fmaf(a1, b_[j], acc[1][j]);
      }
    }
    __syncthreads();
  }
#pragma unroll
  for (int i=0;i<2;i++){
    const int row = bm + ty*2 + i;
#pragma unroll
    for (int j=0;j<4;j++){
      const int col = bn + tx*4 + j;
      if (col < CNCLS){
        float bias = (col < CNREL) ? fc2b[col] : fc3b[col-CNREL];
        out[(size_t)row*CNCLS + col] = acc[i][j] + bias;
      }
    }
  }
}

// ---------------- CE per row + in-place BIG mask (log_softmax is shift-invariant) --------
__global__ __launch_bounds__(256)
void k_ce(float* __restrict__ fcp, const float* __restrict__ gt,
          const int* __restrict__ mask_type, float* __restrict__ cer, float* __restrict__ cet)
{
  __shared__ float red[8];
  const int b = blockIdx.x, tid = threadIdx.x;
  float* row = fcp + (size_t)b*CNCLS;
  const float* g = gt + (size_t)b*CNCLS;
  // relation segment [0,500)
  float mx = -3.0e38f;
  for (int c=tid;c<CNREL;c+=256) mx = fmaxf(mx, row[c]);
  mx = blk_max(mx, red);
  float se=0.f, dt=0.f, gs=0.f;
  for (int c=tid;c<CNREL;c+=256){ float f=row[c], gv=g[c]; se+=expf(f-mx); dt=fmaf(gv,f,dt); gs+=gv; }
  se = blk_sum(se, red); dt = blk_sum(dt, red); gs = blk_sum(gs, red);
  if (tid==0) cer[b] = mx + logf(se) - dt/gs;
  // type segment [500,1500)
  float mx2 = -3.0e38f;
  for (int c=CNREL+tid;c<CNCLS;c+=256) mx2 = fmaxf(mx2, row[c]);
  mx2 = blk_max(mx2, red);
  float se2=0.f, dt2=0.f, gs2=0.f;
  for (int c=CNREL+tid;c<CNCLS;c+=256){ float f=row[c], gv=g[c]; se2+=expf(f-mx2); dt2=fmaf(gv,f,dt2); gs2+=gv; }
  se2 = blk_sum(se2, red); dt2 = blk_sum(dt2, red); gs2 = blk_sum(gs2, red);
  if (tid==0) cet[b] = mx2 + logf(se2) - dt2/gs2;
  __syncthreads();
  if (mask_type[b]==1){ for (int c=tid;c<CNREL;c+=256) row[c] -= BIGF; }
  else                { for (int c=CNREL+tid;c<CNCLS;c+=256) row[c] -= BIGF; }
}

__global__ __launch_bounds__(256)
void k_loss(const float* __restrict__ cer, const float* __restrict__ cet,
            const int* __restrict__ mask_type, float* __restrict__ outp)
{
  __shared__ float red[8];
  const int tid = threadIdx.x;
  float sr=0.f, st=0.f, nr=0.f, nt=0.f;
  for (int b=tid;b<CB;b+=256){
    int mt = mask_type[b];
    if (mt==-1){ sr += cer[b]; nr += 1.f; }
    else if (mt==1){ st += cet[b]; nt += 1.f; }
  }
  sr = blk_sum(sr, red); st = blk_sum(st, red);
  nr = blk_sum(nr, red); nt = blk_sum(nt, red);
  if (tid==0) outp[0] = sr/fmaxf(nr,1.f) + st/fmaxf(nt,1.f);
}

// ---------------- host orchestration ----------------
extern "C" void kernel_launch(void* const* d_in, const int* in_sizes, int n_in,
                              void* d_out, int out_size, void* d_ws, size_t ws_size,
                              hipStream_t stream)
{
  (void)in_sizes; (void)n_in; (void)out_size; (void)ws_size;
  const int*   input_ids  = (const int*)  d_in[0];
  const float* input_mask = (const float*)d_in[1];
  const int*   edge_labels= (const int*)  d_in[2];
  const int*   mask_pos   = (const int*)  d_in[3];
  /* d_in[4] mask_label unused */
  const int*   mask_type  = (const int*)  d_in[5];
  const int*   ent_types  = (const int*)  d_in[6];
  const float* gtruth     = (const float*)d_in[7];
  const int*   l2m        = (const int*)  d_in[8];
  const float* emb        = (const float*)d_in[9];
  const float* ln1g=(const float*)d_in[10], *ln1b=(const float*)d_in[11];
  const float* ln2g=(const float*)d_in[12], *ln2b=(const float*)d_in[13];
  const float* fc2b=(const float*)d_in[14], *fc3b=(const float*)d_in[15];
  const float* ektab=(const float*)d_in[16], *evtab=(const float*)d_in[17];
  const float* g1W=(const float*)d_in[18], *g1as=(const float*)d_in[19], *g1ad=(const float*)d_in[20];
  const float* g2W=(const float*)d_in[21], *g2as=(const float*)d_in[22], *g2ad=(const float*)d_in[23];
  const float* wqkv=(const float*)d_in[24], *wo=(const float*)d_in[25];
  const float* el1g=(const float*)d_in[26], *el1b=(const float*)d_in[27];
  const float* w1=(const float*)d_in[28], *b1=(const float*)d_in[29];
  const float* w2=(const float*)d_in[30], *b2=(const float*)d_in[31];
  const float* el2g=(const float*)d_in[32], *el2b=(const float*)d_in[33];

  char* wsb = (char*)d_ws;
  size_t off = 0;
  auto alloc = [&](size_t bytes)->char*{
    char* p = wsb + off;
    off += (bytes + 255) & ~(size_t)255;
    return p;
  };
  int*   itt  = (int*)  alloc((size_t)NN*CSP*4);
  float* TW1  = (float*)alloc((size_t)NTAB*CD*4);
  float* Ts1  = (float*)alloc(NTAB*4);
  float* Tt1  = (float*)alloc(NTAB*4);
  float* TW2  = (float*)alloc((size_t)NTAB*CD*4);
  float* Ts2  = (float*)alloc(NTAB*4);
  float* Tt2  = (float*)alloc(NTAB*4);
  float* g1o  = (float*)alloc((size_t)NN*CD*4);   // g1; later reused as g2
  float* G1W  = (float*)alloc((size_t)NN*CD*4);
  float* G1s  = (float*)alloc(NN*4);
  float* G1t  = (float*)alloc(NN*4);
  float* G1rs = (float*)alloc(NN*4);
  float* xb   = (float*)alloc((size_t)NSR*CD*4);
  float* yb   = (float*)alloc((size_t)NSR*CD*4);
  float* qkvb = (float*)alloc((size_t)NSR*3*CD*4);
  float* ctxb = (float*)alloc((size_t)NSR*CD*4);
  float* cer  = (float*)alloc(CB*4);
  float* cet  = (float*)alloc(CB*4);
  float* ffh  = qkvb;   // alias: qkv dead once attn has consumed it
  float* g2o  = g1o;    // alias: raw g1 dead after k_g1post
  float* hm   = ctxb;   // alias: ctx dead after the encoder

  float* dout = (float*)d_out;
  float* fcp  = dout + 1;   // fc_out; dout[0] = loss

  // ---- GAT pipeline ----
  k_typeprep<<<dim3((NN*CSP+255)/256),dim3(256),0,stream>>>(input_ids, ent_types, itt);
  k_tables<<<dim3(NTAB),dim3(256),0,stream>>>(emb, g1W, g1as, g1ad, TW1, Ts1, Tt1);
  k_tables<<<dim3(NTAB),dim3(256),0,stream>>>(emb, g2W, g2as, g2ad, TW2, Ts2, Tt2);
  k_gat<10><<<dim3(NN),dim3(256),0,stream>>>(itt, TW1, Ts1, Tt1,
        nullptr, nullptr, nullptr, nullptr, nullptr,
        g1W + CD*CD, g1as + CD, g1ad + CD, g1o);
  k_g1post<<<dim3(NN),dim3(256),0,stream>>>(g1o, g2W, g2as, g2ad, G1W, G1s, G1t, G1rs);
  k_gat<15><<<dim3(NN),dim3(256),0,stream>>>(itt, TW2, Ts2, Tt2,
        G1W, G1s, G1t, G1rs, l2m,
        g2W + CD*CD, g2as + CD, g2ad + CD, g2o);
  k_x0<<<dim3(NSR),dim3(256),0,stream>>>(input_ids, mask_pos, mask_type, emb, g2o, ln1g, ln1b, xb);

  // ---- encoder (12 layers) ----
  for (int l=0;l<CL;l++){
    const float* wqkv_l = wqkv + (size_t)l*CD*3*CD;
    const float* wo_l   = wo   + (size_t)l*CD*CD;
    const float* w1_l   = w1   + (size_t)l*CD*512;
    const float* b1_l   = b1   + (size_t)l*512;
    const float* w2_l   = w2   + (size_t)l*512*CD;
    const float* b2_l   = b2   + (size_t)l*CD;
    k_gemm<0,false,false><<<dim3(12,352),dim3(256),0,stream>>>(xb, wqkv_l, nullptr, nullptr, qkvb, NSR, 768, 256);
    k_attn<<<dim3(CB*CH),dim3(128),0,stream>>>(qkvb, edge_labels, ektab, evtab, input_mask, ctxb);
    k_gemm<0,false,true><<<dim3(4,352),dim3(256),0,stream>>>(ctxb, wo_l, nullptr, xb, yb, NSR, 256, 256);
    k_ln<<<dim3(NSR),dim3(256),0,stream>>>(yb, xb, el1g + (size_t)l*CD, el1b + (size_t)l*CD, 1e-12f);
    k_gemm<1,true,false><<<dim3(8,352),dim3(256),0,stream>>>(xb, w1_l, b1_l, nullptr, ffh, NSR, 512, 256);
    k_gemm<0,true,true><<<dim3(4,352),dim3(256),0,stream>>>(ffh, w2_l, b2_l, xb, yb, NSR, 256, 512);
    k_ln<<<dim3(NSR),dim3(256),0,stream>>>(yb, xb, el2g + (size_t)l*CD, el2b + (size_t)l*CD, 1e-12f);
  }

  // ---- head / classifier / loss ----
  k_head<<<dim3(CB),dim3(256),0,stream>>>(xb, mask_pos, ln2g, ln2b, hm);
  k_fc<<<dim3((CNCLS+63)/64, CB/32),dim3(256),0,stream>>>(hm, emb, fc2b, fc3b, fcp);
  k_ce<<<dim3(CB),dim3(256),0,stream>>>(fcp, gtruth, mask_type, cer, cet);
  k_loss<<<dim3(1),dim3(256),0,stream>>>(cer, cet, mask_type, dout);
}